// Round 2
// baseline (531.709 us; speedup 1.0000x reference)
//
#include <hip/hip_runtime.h>
#include <hip/hip_bf16.h>
#include <hip/hip_cooperative_groups.h>

namespace cg = cooperative_groups;

typedef __bf16 bf16;
typedef __bf16 bf16x8 __attribute__((ext_vector_type(8)));
typedef float floatx4 __attribute__((ext_vector_type(4)));

#define B_ROWS 4096
#define IN_DIM 512
#define DIM 1024
#define NG 10

__device__ __forceinline__ float geluf(float x) {
    return 0.5f * x * (1.0f + erff(x * 0.70710678118654752f));
}

// async global->LDS, 16B per lane; LDS dest = wave-uniform base + lane*16
__device__ __forceinline__ void async16(void* lds, const void* g) {
    __builtin_amdgcn_global_load_lds(
        (const __attribute__((address_space(1))) unsigned int*)g,
        (__attribute__((address_space(3))) unsigned int*)lds, 16, 0, 0);
}
// s_waitcnt vmcnt(N) only (lgkm=15, exp=7 -> no wait): imm = 0x0F70|N
#define WAIT_VM(N) __builtin_amdgcn_s_waitcnt(0x0F70 | (N))
#define BARRIER() __builtin_amdgcn_s_barrier()

// ---------------------------------------------------------------------------
// prep body: ng = bf16( mu[g] + (|sigma[g]|+eps) * z ). Pure elementwise.
// pb in [0,1024): 256 threads x 8 floats each.
// ---------------------------------------------------------------------------
__device__ __forceinline__ void prep_body(int pb, const int* __restrict__ genre,
                                          const float* __restrict__ z,
                                          const float* __restrict__ mu_t,
                                          const float* __restrict__ sg_t,
                                          bf16* __restrict__ ng) {
    const int t = pb * 256 + threadIdx.x;
    const int row = t >> 6;
    const int c0 = (t & 63) * 8;
    const int g = genre[row];
    const float* zp = z + (size_t)row * IN_DIM + c0;
    const float* mp = mu_t + (size_t)g * IN_DIM + c0;
    const float* sp = sg_t + (size_t)g * IN_DIM + c0;
    floatx4 z0 = *(const floatx4*)zp, z1 = *(const floatx4*)(zp + 4);
    floatx4 m0 = *(const floatx4*)mp, m1 = *(const floatx4*)(mp + 4);
    floatx4 s0 = *(const floatx4*)sp, s1 = *(const floatx4*)(sp + 4);
    bf16x8 o;
#pragma unroll
    for (int i = 0; i < 4; i++) {
        o[i] = (bf16)(m0[i] + (fabsf(s0[i]) + 1e-8f) * z0[i]);
        o[i + 4] = (bf16)(m1[i] + (fabsf(s1[i]) + 1e-8f) * z1[i]);
    }
    *(bf16x8*)(ng + (size_t)row * IN_DIM + c0) = o;
}

// ---------------------------------------------------------------------------
// bucket body (256 thr): per-wave histograms, serial prefix on thread 0
// (which also builds the expert tile list: (g<<8)|(by<<3)|bx, <=512 tiles),
// per-wave-base scatter.
// ---------------------------------------------------------------------------
__device__ __forceinline__ void bucket_body(const int* __restrict__ genre,
                                            int* __restrict__ counts,
                                            int* __restrict__ offsets,
                                            int* __restrict__ row_ids,
                                            int* __restrict__ ntile,
                                            int* __restrict__ tlist, int* sh) {
    int* whist = sh;           // [4][NG]
    int* wbase = sh + 4 * NG;  // [4][NG]
    const int tid = threadIdx.x;
    const int wave = tid >> 6;
    if (tid < 4 * NG) whist[tid] = 0;
    __syncthreads();
    int g[16];
#pragma unroll
    for (int i = 0; i < 16; i++) {
        g[i] = genre[tid + i * 256];
        atomicAdd(&whist[wave * NG + g[i]], 1);
    }
    __syncthreads();
    if (tid == 0) {
        int acc = 0;
        int n = 0;
        for (int e = 0; e < NG; e++) {
            int tot = 0;
            for (int w = 0; w < 4; w++) {
                wbase[w * NG + e] = acc + tot;
                tot += whist[w * NG + e];
            }
            counts[e] = tot;
            offsets[e] = acc;
            acc += tot;
            const int nb = (tot + 127) >> 7;
            for (int by = 0; by < nb; by++)
                for (int bx = 0; bx < 8; bx++)
                    tlist[n++] = (e << 8) | (by << 3) | bx;
        }
        offsets[NG] = acc;
        *ntile = n;
    }
    __syncthreads();
#pragma unroll
    for (int i = 0; i < 16; i++) {
        int pos = atomicAdd(&wbase[wave * NG + g[i]], 1);
        row_ids[pos] = tid + i * 256;
    }
    __syncthreads();
}

// ---------------------------------------------------------------------------
// transpose body: 2 row-adjacent 64x64 tiles of [R][1024] fp32 ->
// [1024][R] bf16 (32 KB LDS, XOR swizzle). Trailing sync so the LDS buffer
// can be immediately reused by the caller.
// ---------------------------------------------------------------------------
__device__ __forceinline__ void transpose_body(const float* __restrict__ src,
                                               bf16* __restrict__ dst, int R,
                                               int b, float* T /*[2][4096]*/) {
    const int r0 = (b >> 4) * 128;
    const int c0 = (b & 15) * 64;
    const int tid = threadIdx.x;
#pragma unroll
    for (int t = 0; t < 2; t++)
#pragma unroll
        for (int i = 0; i < 4; i++) {
            const int s = i * 256 + tid;
            const int r = s >> 4;
            const int cv = s & 15;
            floatx4 v = *(const floatx4*)(src + (size_t)(r0 + t * 64 + r) * 1024 +
                                          c0 + cv * 4);
            *(floatx4*)(T + t * 4096 + r * 64 + ((cv ^ (r >> 3)) * 4)) = v;
        }
    __syncthreads();
#pragma unroll
    for (int t = 0; t < 2; t++)
#pragma unroll
        for (int i = 0; i < 2; i++) {
            const int s = i * 256 + tid;
            const int oc = s >> 3;
            const int og = s & 7;
            const int cg = oc >> 2, o = oc & 3;
            bf16x8 v;
#pragma unroll
            for (int u = 0; u < 8; u++) {
                const int r = og * 8 + u;
                v[u] = (bf16)T[t * 4096 + r * 64 + ((cg ^ (r >> 3)) * 4) + o];
            }
            *(bf16x8*)(dst + (size_t)(c0 + oc) * R + r0 + t * 64 + og * 8) = v;
        }
    __syncthreads();
}

// ---------------------------------------------------------------------------
// GEMM body: C = act(A @ BT^T + bias). A [M][K] bf16, BT [N][K] bf16.
// 128M x BN tile (BN=64 or 128), 4 waves, BK=64, DOUBLE-BUFFERED async
// staging with counted vmcnt: issue (4+NB) loads into nxt, wait only cur's
// loads, barrier, compute, barrier. Source-side XOR octet swizzle ->
// fragment ds_read_b128 2-way max (free).
// ---------------------------------------------------------------------------
template <int BN, bool EXPERT, bool GATHER_A, bool SCATTER_C, bool GELU,
          typename CT>
__device__ __forceinline__ void gemm_body(
    int bx, int by, int gz, const bf16* __restrict__ A,
    const bf16* __restrict__ BT, const float* __restrict__ bias,
    CT* __restrict__ Cmat, int N, int K, const int* __restrict__ row_ids,
    const int* __restrict__ offsets, const int* __restrict__ counts,
    bf16* As, bf16* Bs) {
    constexpr int BK = 64;        // 8 octets per row
    constexpr int NB = BN / 32;   // B staging issues (2 or 4)
    constexpr int NJ = BN / 32;   // j-fragments per wave (2 or 4)
    constexpr int ABUF = 128 * BK;  // elems per A buffer
    constexpr int BBUF = BN * BK;   // elems per B buffer

    int off = 0, cnt = 1 << 30;
    if (EXPERT) {
        cnt = counts[gz];
        if (by * 128 >= cnt) return;
        off = offsets[gz];
        BT += (size_t)gz * N * K;
        bias += (size_t)gz * N;
    }
    const int m_start = by * 128;
    const int n0 = bx * BN;

    const int tid = threadIdx.x;
    const int lane = tid & 63;
    const int wave = tid >> 6;
    const int wrow = (wave >> 1) * 64;
    const int wcol = (wave & 1) * (BN / 2);
    const int quad = lane >> 4;
    const int l16 = lane & 15;

    // A staging: 1024 slots (128 rows x 8 octets), 4 issues of 256
    const bf16* a_src[4];
#pragma unroll
    for (int i = 0; i < 4; i++) {
        const int s = i * 256 + tid;
        const int row = s >> 3;
        const int col = ((s & 7) ^ (row & 7)) * 8;
        int p = m_start + row;
        size_t arow;
        if (EXPERT) {
            int pp = off + min(p, cnt - 1);
            arow = GATHER_A ? (size_t)row_ids[pp] : (size_t)pp;
        } else {
            arow = (size_t)p;
        }
        a_src[i] = A + arow * (size_t)K + col;
    }
    // B staging: BN*8 slots, NB issues of 256
    const bf16* b_src[NB];
#pragma unroll
    for (int i = 0; i < NB; i++) {
        const int s = i * 256 + tid;
        const int row = s >> 3;
        const int col = ((s & 7) ^ (row & 7)) * 8;
        b_src[i] = BT + (size_t)(n0 + row) * K + col;
    }
    const int ldsbase = wave * 512;  // elems; HW adds lane*16B

    floatx4 acc[4][NJ];
#pragma unroll
    for (int i = 0; i < 4; i++)
#pragma unroll
        for (int j = 0; j < NJ; j++)
#pragma unroll
            for (int r = 0; r < 4; r++) acc[i][j][r] = 0.0f;

    const int nK = K / BK;
    // prologue: k=0 into buf0
#pragma unroll
    for (int i = 0; i < 4; i++) async16(&As[i * 2048 + ldsbase], a_src[i]);
#pragma unroll
    for (int i = 0; i < NB; i++) async16(&Bs[i * 2048 + ldsbase], b_src[i]);

    for (int kt = 0; kt < nK; kt++) {
        const int cur = kt & 1, nxt = cur ^ 1;
        const int kn = (kt + 1 < nK) ? (kt + 1) * BK : 0;  // clamp: harmless
#pragma unroll
        for (int i = 0; i < 4; i++)
            async16(&As[nxt * ABUF + i * 2048 + ldsbase], a_src[i] + kn);
#pragma unroll
        for (int i = 0; i < NB; i++)
            async16(&Bs[nxt * BBUF + i * 2048 + ldsbase], b_src[i] + kn);
        WAIT_VM(4 + NB);  // cur's loads done; nxt's still in flight
        BARRIER();
#pragma unroll
        for (int ks = 0; ks < 2; ks++) {
            bf16x8 af[4], bfr[NJ];
            const int cb = ks * 4 + quad;
#pragma unroll
            for (int i = 0; i < 4; i++) {
                const int r = wrow + i * 16 + l16;
                af[i] = *(const bf16x8*)(&As[cur * ABUF + (r * 8 + (cb ^ (r & 7))) * 8]);
            }
#pragma unroll
            for (int j = 0; j < NJ; j++) {
                const int n = wcol + j * 16 + l16;
                bfr[j] = *(const bf16x8*)(&Bs[cur * BBUF + (n * 8 + (cb ^ (n & 7))) * 8]);
            }
#pragma unroll
            for (int i = 0; i < 4; i++)
#pragma unroll
                for (int j = 0; j < NJ; j++)
                    acc[i][j] = __builtin_amdgcn_mfma_f32_16x16x32_bf16(
                        af[i], bfr[j], acc[i][j], 0, 0, 0);
        }
        BARRIER();  // protect cur before next iter overwrites it
    }

    // epilogue: C/D layout col = lane&15, row = quad*4 + reg  [m89-verified]
#pragma unroll
    for (int j = 0; j < NJ; j++) {
        const int n = n0 + wcol + j * 16 + l16;
        const float bv = bias[n];
#pragma unroll
        for (int i = 0; i < 4; i++) {
            const int rbase = wrow + i * 16 + quad * 4;
#pragma unroll
            for (int r = 0; r < 4; r++) {
                const int p = m_start + rbase + r;
                if (EXPERT && p >= cnt) continue;
                float v = acc[i][j][r] + bv;
                if (GELU) v = geluf(v);
                size_t drow;
                if (EXPERT) {
                    const int pp = off + p;
                    drow = SCATTER_C ? (size_t)row_ids[pp] : (size_t)pp;
                } else {
                    drow = (size_t)p;
                }
                Cmat[drow * (size_t)N + n] = (CT)v;
            }
        }
    }
}

// ---------------------------------------------------------------------------
// MONO persistent cooperative kernel: 512 blocks x 256 threads, 64 KB LDS
// (2 blocks/CU -> guaranteed co-resident). 5 phases with grid.sync():
//  P0: prep (2 units/block) + Ws1/Ws2 transpose + bucket(+tile list)
//  P1: gemm1 (512 tiles of 128Mx64N, K=512)  + We1 transpose (1280 units)
//  P2: gemm2 (512 tiles of 128Mx64N, K=1024) + We2 transpose (1280 units)
//  P3: expert1 (tile list, <=512 tiles of 128x128, gather A, gelu -> hp)
//  P4: expert2 (tile list, scatter C -> fp32 out)
// ---------------------------------------------------------------------------
__global__ __launch_bounds__(256, 2) void mono_kernel(
    const int* __restrict__ genre, const float* __restrict__ z,
    const float* __restrict__ mu_t, const float* __restrict__ sg_t,
    const float* __restrict__ Ws1, const float* __restrict__ bs1,
    const float* __restrict__ Ws2, const float* __restrict__ bs2,
    const float* __restrict__ We1, const float* __restrict__ be1,
    const float* __restrict__ We2, const float* __restrict__ be2,
    float* __restrict__ out, char* __restrict__ w) {
    __shared__ bf16 smem[32768];  // 64 KB
    cg::grid_group grid = cg::this_grid();
    const int b = blockIdx.x;

    int* counts = (int*)w;
    int* offsets = (int*)(w + 64);
    int* ntile = (int*)(w + 128);
    int* tlist = (int*)(w + 256);
    int* row_ids = (int*)(w + 4096);
    char* wb = w + (64 << 10);
    bf16* ng = (bf16*)wb;                          // [4096][512]  4 MB
    bf16* hp = (bf16*)wb;                          // [4096][1024] 8 MB (aliases ng+s1 head; both dead by P3)
    bf16* s1 = (bf16*)(wb + ((size_t)4 << 20));    // 8 MB
    bf16* s2 = (bf16*)(wb + ((size_t)12 << 20));   // 8 MB
    bf16* WT1 = (bf16*)(wb + ((size_t)20 << 20));  // 1 MB
    bf16* WT2 = WT1 + (size_t)IN_DIM * DIM;        // 2 MB
    bf16* WE1T = WT2 + (size_t)DIM * DIM;          // 20 MB
    bf16* WE2T = WE1T + (size_t)NG * DIM * DIM;    // 20 MB

    // ---- Phase 0: prep + shared-weight transposes + bucket ----
    prep_body(b, genre, z, mu_t, sg_t, ng);
    prep_body(b + 512, genre, z, mu_t, sg_t, ng);
    if (b < 64) {
        transpose_body(Ws1, WT1, 512, b, (float*)smem);
    } else if (b < 192) {
        transpose_body(Ws2, WT2, 1024, b - 64, (float*)smem);
    } else if (b == 192) {
        bucket_body(genre, counts, offsets, row_ids, ntile, tlist, (int*)smem);
    }
    grid.sync();

    // ---- Phase 1: shared MLP layer 1 (K=512)  ||  transpose We1 ----
    gemm_body<64, false, false, false, true, bf16>(
        b & 15, b >> 4, 0, ng, WT1, bs1, s1, DIM, IN_DIM, nullptr, nullptr,
        nullptr, smem, smem + 16384);
    for (int u = b; u < 1280; u += 512) {
        const int e = u >> 7;
        transpose_body(We1 + (size_t)e * DIM * DIM, WE1T + (size_t)e * DIM * DIM,
                       1024, u & 127, (float*)smem);
    }
    grid.sync();

    // ---- Phase 2: shared MLP layer 2 (K=1024)  ||  transpose We2 ----
    gemm_body<64, false, false, false, true, bf16>(
        b & 15, b >> 4, 0, s1, WT2, bs2, s2, DIM, DIM, nullptr, nullptr,
        nullptr, smem, smem + 16384);
    for (int u = b; u < 1280; u += 512) {
        const int e = u >> 7;
        transpose_body(We2 + (size_t)e * DIM * DIM, WE2T + (size_t)e * DIM * DIM,
                       1024, u & 127, (float*)smem);
    }
    grid.sync();

    // ---- Phase 3: expert layer 1 (gather, gelu -> permuted hp) ----
    int nt = *ntile;
    if (b < nt) {
        const int t = tlist[b];
        gemm_body<128, true, true, false, true, bf16>(
            t & 7, (t >> 3) & 31, t >> 8, s2, WE1T, be1, hp, DIM, DIM, row_ids,
            offsets, counts, smem, smem + 16384);
    }
    grid.sync();

    // ---- Phase 4: expert layer 2 (contiguous hp, scatter -> fp32 out) ----
    if (b < nt) {
        const int t = tlist[b];
        gemm_body<128, true, false, true, false, float>(
            t & 7, (t >> 3) & 31, t >> 8, hp, WE2T, be2, out, DIM, DIM, row_ids,
            offsets, counts, smem, smem + 16384);
    }
}

// ---------------------------------------------------------------------------
// Fallback path (round-1 structure) in case cooperative launch fails under
// graph capture.
// ---------------------------------------------------------------------------
__global__ void setup_kernel(const int* __restrict__ genre,
                             const float* __restrict__ z,
                             const float* __restrict__ mu_t,
                             const float* __restrict__ sg_t,
                             bf16* __restrict__ ng,
                             const float* __restrict__ Ws1,
                             const float* __restrict__ Ws2,
                             bf16* __restrict__ WT1, bf16* __restrict__ WT2,
                             int* __restrict__ counts,
                             int* __restrict__ offsets,
                             int* __restrict__ row_ids,
                             int* __restrict__ ntile,
                             int* __restrict__ tlist) {
    __shared__ float T[2 * 4096];
    const int b = blockIdx.x;
    if (b == 0) {
        bucket_body(genre, counts, offsets, row_ids, ntile, tlist, (int*)T);
    } else if (b < 1025) {
        prep_body(b - 1, genre, z, mu_t, sg_t, ng);
    } else if (b < 1089) {
        transpose_body(Ws1, WT1, 512, b - 1025, T);
    } else {
        transpose_body(Ws2, WT2, 1024, b - 1089, T);
    }
}

__global__ __launch_bounds__(256, 2) void mlp_fused_kernel(
    const bf16* __restrict__ Ain, const bf16* __restrict__ WT,
    const float* __restrict__ bias, bf16* __restrict__ Sout,
    const float* __restrict__ We, bf16* __restrict__ WET, int K) {
    __shared__ bf16 smem[32768];
    int b = blockIdx.x;
    if (b < 512) {
        gemm_body<64, false, false, false, true, bf16>(
            b & 15, b >> 4, 0, Ain, WT, bias, Sout, DIM, K, nullptr, nullptr,
            nullptr, smem, smem + 16384);
    } else {
        b -= 512;
        const int e = b >> 7;
        transpose_body(We + (size_t)e * DIM * DIM, WET + (size_t)e * DIM * DIM,
                       1024, b & 127, (float*)smem);
    }
}

template <bool GATHER_A, bool SCATTER_C, bool GELU, typename CT>
__global__ __launch_bounds__(256, 2) void expert_gemm_kernel(
    const bf16* __restrict__ A, const bf16* __restrict__ BT,
    const float* __restrict__ bias, CT* __restrict__ Cmat,
    const int* __restrict__ row_ids, const int* __restrict__ offsets,
    const int* __restrict__ counts) {
    __shared__ bf16 smem[32768];
    gemm_body<128, GATHER_A, SCATTER_C, GELU, true, CT>(  // placeholder; fixed below
        0, 0, 0, A, BT, bias, Cmat, DIM, DIM, row_ids, offsets, counts, smem,
        smem + 16384);
}

// The template juggling above is error-prone; use explicit wrappers instead.
template <bool GATHER_A, bool SCATTER_C, bool GELU, typename CT>
__global__ __launch_bounds__(256, 2) void expert_gemm2_kernel(
    const bf16* __restrict__ A, const bf16* __restrict__ BT,
    const float* __restrict__ bias, CT* __restrict__ Cmat,
    const int* __restrict__ row_ids, const int* __restrict__ offsets,
    const int* __restrict__ counts) {
    __shared__ bf16 smem[32768];
    gemm_body<128, true, GATHER_A, SCATTER_C, GELU, CT>(
        blockIdx.x, blockIdx.y, blockIdx.z, A, BT, bias, Cmat, DIM, DIM,
        row_ids, offsets, counts, smem, smem + 16384);
}

extern "C" void kernel_launch(void* const* d_in, const int* in_sizes, int n_in,
                              void* d_out, int out_size, void* d_ws,
                              size_t ws_size, hipStream_t stream) {
    const int* genre = (const int*)d_in[1];
    const float* z = (const float*)d_in[2];
    const float* mu_t = (const float*)d_in[3];
    const float* sg_t = (const float*)d_in[4];
    const float* Ws1 = (const float*)d_in[5];
    const float* bs1 = (const float*)d_in[6];
    const float* Ws2 = (const float*)d_in[7];
    const float* bs2 = (const float*)d_in[8];
    const float* We1 = (const float*)d_in[9];
    const float* be1 = (const float*)d_in[10];
    const float* We2 = (const float*)d_in[11];
    const float* be2 = (const float*)d_in[12];
    float* out = (float*)d_out;
    char* w = (char*)d_ws;

    void* kargs[] = {(void*)&genre, (void*)&z,   (void*)&mu_t, (void*)&sg_t,
                     (void*)&Ws1,   (void*)&bs1, (void*)&Ws2,  (void*)&bs2,
                     (void*)&We1,   (void*)&be1, (void*)&We2,  (void*)&be2,
                     (void*)&out,   (void*)&w};
    hipError_t err = hipLaunchCooperativeKernel(
        (const void*)mono_kernel, dim3(512), dim3(256), kargs, 0, stream);
    if (err == hipSuccess) return;

    // ---- fallback: 5-dispatch path ----
    int* counts = (int*)w;
    int* offsets = (int*)(w + 64);
    int* ntile = (int*)(w + 128);
    int* tlist = (int*)(w + 256);
    int* row_ids = (int*)(w + 4096);
    char* wb = w + (64 << 10);
    bf16* ng = (bf16*)wb;
    bf16* hp = (bf16*)wb;
    bf16* s1 = (bf16*)(wb + ((size_t)4 << 20));
    bf16* s2 = (bf16*)(wb + ((size_t)12 << 20));
    bf16* WT1 = (bf16*)(wb + ((size_t)20 << 20));
    bf16* WT2 = WT1 + (size_t)IN_DIM * DIM;
    bf16* WE1T = WT2 + (size_t)DIM * DIM;
    bf16* WE2T = WE1T + (size_t)NG * DIM * DIM;

    setup_kernel<<<1217, 256, 0, stream>>>(genre, z, mu_t, sg_t, ng, Ws1, Ws2,
                                           WT1, WT2, counts, offsets, row_ids,
                                           ntile, tlist);
    mlp_fused_kernel<<<1792, 256, 0, stream>>>(ng, WT1, bs1, s1, We1, WE1T,
                                               IN_DIM);
    mlp_fused_kernel<<<1792, 256, 0, stream>>>(s1, WT2, bs2, s2, We2, WE2T,
                                               DIM);
    expert_gemm2_kernel<true, false, true, bf16>
        <<<dim3(8, 32, 10), 256, 0, stream>>>(s2, WE1T, be1, hp, row_ids,
                                              offsets, counts);
    expert_gemm2_kernel<false, true, false, float>
        <<<dim3(8, 32, 10), 256, 0, stream>>>(hp, WE2T, be2, out, row_ids,
                                              offsets, counts);
}

// Round 7
// 247.187 us; speedup vs baseline: 2.1510x; 2.1510x over previous
//
#include <hip/hip_runtime.h>
#include <hip/hip_bf16.h>

typedef __bf16 bf16;
typedef __bf16 bf16x8 __attribute__((ext_vector_type(8)));
typedef float floatx4 __attribute__((ext_vector_type(4)));

#define B_ROWS 4096
#define IN_DIM 512
#define DIM 1024
#define NG 10

__device__ __forceinline__ float geluf(float x) {
    return 0.5f * x * (1.0f + erff(x * 0.70710678118654752f));
}

// async global->LDS, 16B per lane; LDS dest = wave-uniform base + lane*16
__device__ __forceinline__ void async16(void* lds, const void* g) {
    __builtin_amdgcn_global_load_lds(
        (const __attribute__((address_space(1))) unsigned int*)g,
        (__attribute__((address_space(3))) unsigned int*)lds, 16, 0, 0);
}
// s_waitcnt vmcnt(N) only (lgkm=15, exp=7 -> no wait): imm = 0x0F70|N
#define WAIT_VM(N) __builtin_amdgcn_s_waitcnt(0x0F70 | (N))
#define BARRIER() __builtin_amdgcn_s_barrier()

// ---------------------------------------------------------------------------
// prep body: ng = bf16( mu[g] + (|sigma[g]|+eps) * z ). Pure elementwise.
// pb in [0,1024): 256 threads x 8 floats each.
// ---------------------------------------------------------------------------
__device__ __forceinline__ void prep_body(int pb, const int* __restrict__ genre,
                                          const float* __restrict__ z,
                                          const float* __restrict__ mu_t,
                                          const float* __restrict__ sg_t,
                                          bf16* __restrict__ ng) {
    const int t = pb * 256 + threadIdx.x;
    const int row = t >> 6;
    const int c0 = (t & 63) * 8;
    const int g = genre[row];
    const float* zp = z + (size_t)row * IN_DIM + c0;
    const float* mp = mu_t + (size_t)g * IN_DIM + c0;
    const float* sp = sg_t + (size_t)g * IN_DIM + c0;
    floatx4 z0 = *(const floatx4*)zp, z1 = *(const floatx4*)(zp + 4);
    floatx4 m0 = *(const floatx4*)mp, m1 = *(const floatx4*)(mp + 4);
    floatx4 s0 = *(const floatx4*)sp, s1 = *(const floatx4*)(sp + 4);
    bf16x8 o;
#pragma unroll
    for (int i = 0; i < 4; i++) {
        o[i] = (bf16)(m0[i] + (fabsf(s0[i]) + 1e-8f) * z0[i]);
        o[i + 4] = (bf16)(m1[i] + (fabsf(s1[i]) + 1e-8f) * z1[i]);
    }
    *(bf16x8*)(ng + (size_t)row * IN_DIM + c0) = o;
}

// ---------------------------------------------------------------------------
// bucket body (256 thr): per-wave histograms (4x less same-address atomic
// contention than single hist), serial prefix on thread 0, per-wave-base
// scatter. Order within a bucket is arbitrary (gather/scatter both use
// row_ids consistently).
// ---------------------------------------------------------------------------
__device__ __forceinline__ void bucket_body(const int* __restrict__ genre,
                                            int* __restrict__ counts,
                                            int* __restrict__ offsets,
                                            int* __restrict__ row_ids,
                                            int* sh) {
    int* whist = sh;           // [4][NG]
    int* wbase = sh + 4 * NG;  // [4][NG]
    const int tid = threadIdx.x;
    const int wave = tid >> 6;
    if (tid < 4 * NG) whist[tid] = 0;
    __syncthreads();
    int g[16];
#pragma unroll
    for (int i = 0; i < 16; i++) {
        g[i] = genre[tid + i * 256];
        atomicAdd(&whist[wave * NG + g[i]], 1);
    }
    __syncthreads();
    if (tid == 0) {
        int acc = 0;
        for (int e = 0; e < NG; e++) {
            int tot = 0;
            for (int w = 0; w < 4; w++) {
                wbase[w * NG + e] = acc + tot;
                tot += whist[w * NG + e];
            }
            counts[e] = tot;
            offsets[e] = acc;
            acc += tot;
        }
        offsets[NG] = acc;
    }
    __syncthreads();
#pragma unroll
    for (int i = 0; i < 16; i++) {
        int pos = atomicAdd(&wbase[wave * NG + g[i]], 1);
        row_ids[pos] = tid + i * 256;
    }
}

// ---------------------------------------------------------------------------
// transpose body: 2 row-adjacent 64x64 tiles of [R][1024] fp32 ->
// [1024][R] bf16 (32 KB LDS, XOR swizzle).
// ---------------------------------------------------------------------------
__device__ __forceinline__ void transpose_body(const float* __restrict__ src,
                                               bf16* __restrict__ dst, int R,
                                               int b, float* T /*[2][4096]*/) {
    const int r0 = (b >> 4) * 128;
    const int c0 = (b & 15) * 64;
    const int tid = threadIdx.x;
#pragma unroll
    for (int t = 0; t < 2; t++)
#pragma unroll
        for (int i = 0; i < 4; i++) {
            const int s = i * 256 + tid;
            const int r = s >> 4;
            const int cv = s & 15;
            floatx4 v = *(const floatx4*)(src + (size_t)(r0 + t * 64 + r) * 1024 +
                                          c0 + cv * 4);
            *(floatx4*)(T + t * 4096 + r * 64 + ((cv ^ (r >> 3)) * 4)) = v;
        }
    __syncthreads();
#pragma unroll
    for (int t = 0; t < 2; t++)
#pragma unroll
        for (int i = 0; i < 2; i++) {
            const int s = i * 256 + tid;
            const int oc = s >> 3;
            const int og = s & 7;
            const int cg = oc >> 2, o = oc & 3;
            bf16x8 v;
#pragma unroll
            for (int u = 0; u < 8; u++) {
                const int r = og * 8 + u;
                v[u] = (bf16)T[t * 4096 + r * 64 + ((cg ^ (r >> 3)) * 4) + o];
            }
            *(bf16x8*)(dst + (size_t)(c0 + oc) * R + r0 + t * 64 + og * 8) = v;
        }
}

// ---------------------------------------------------------------------------
// GEMM body: C = act(A @ BT^T + bias). A [M][K] bf16, BT [N][K] bf16.
// 128M x 128N tile (m97 geometry: 4 waves, 4x4 frags of 16x16), BK=64,
// DOUBLE-BUFFERED async staging with counted vmcnt: per iter issue 8
// global_load_lds into nxt, s_waitcnt vmcnt(8) (waits only cur's 8), raw
// s_barrier, compute cur (32 MFMA/wave), raw s_barrier. LDS 2x(16+16)KB =
// 64 KB -> 2 blocks/CU. Source-side XOR octet swizzle: slot s ->
// (row=s>>3, oct=(s&7)^(row&7)); fragment ds_read_b128 2-way max (free).
// EXPERT: gz = genre; rows are bucket positions [0,count) at offsets[g].
// ---------------------------------------------------------------------------
template <bool EXPERT, bool GATHER_A, bool SCATTER_C, bool GELU, typename CT>
__device__ __forceinline__ void gemm_body(
    int bx, int by, int gz, const bf16* __restrict__ A,
    const bf16* __restrict__ BT, const float* __restrict__ bias,
    CT* __restrict__ Cmat, int N, int K, const int* __restrict__ row_ids,
    const int* __restrict__ offsets, const int* __restrict__ counts,
    bf16* As /*[2][8192]*/, bf16* Bs /*[2][8192]*/) {
    int off = 0, cnt = 1 << 30;
    if (EXPERT) {
        cnt = counts[gz];
        if (by * 128 >= cnt) return;
        off = offsets[gz];
        BT += (size_t)gz * N * K;
        bias += (size_t)gz * N;
    }
    const int m_start = by * 128;
    const int n0 = bx * 128;

    constexpr int BK = 64;  // 8 octets per row
    const int tid = threadIdx.x;
    const int lane = tid & 63;
    const int wave = tid >> 6;
    const int wrow = (wave >> 1) * 64;
    const int wcol = (wave & 1) * 64;
    const int quad = lane >> 4;
    const int l16 = lane & 15;

    // A staging: 1024 slots (128 rows x 8 octets), 4 issues of 256
    const bf16* a_src[4];
#pragma unroll
    for (int i = 0; i < 4; i++) {
        const int s = i * 256 + tid;
        const int row = s >> 3;
        const int col = ((s & 7) ^ (row & 7)) * 8;
        int p = m_start + row;
        size_t arow;
        if (EXPERT) {
            int pp = off + min(p, cnt - 1);
            arow = GATHER_A ? (size_t)row_ids[pp] : (size_t)pp;
        } else {
            arow = (size_t)p;
        }
        a_src[i] = A + arow * (size_t)K + col;
    }
    // B staging: 1024 slots (128 rows x 8 octets), 4 issues
    const bf16* b_src[4];
#pragma unroll
    for (int i = 0; i < 4; i++) {
        const int s = i * 256 + tid;
        const int row = s >> 3;
        const int col = ((s & 7) ^ (row & 7)) * 8;
        b_src[i] = BT + (size_t)(n0 + row) * K + col;
    }
    const int ldsbase = wave * 512;  // wave-uniform (bf16 units); HW adds lane*16B

    floatx4 acc[4][4];
#pragma unroll
    for (int i = 0; i < 4; i++)
#pragma unroll
        for (int j = 0; j < 4; j++)
#pragma unroll
            for (int r = 0; r < 4; r++) acc[i][j][r] = 0.0f;

    const int nK = K / BK;
    // prologue: k=0 into buf0
#pragma unroll
    for (int i = 0; i < 4; i++) async16(&As[i * 2048 + ldsbase], a_src[i]);
#pragma unroll
    for (int i = 0; i < 4; i++) async16(&Bs[i * 2048 + ldsbase], b_src[i]);

    for (int kt = 0; kt < nK; kt++) {
        const int cur = kt & 1, nxt = cur ^ 1;
        const int kn = (kt + 1 < nK) ? (kt + 1) * BK : 0;  // clamp: harmless
#pragma unroll
        for (int i = 0; i < 4; i++)
            async16(&As[nxt * 8192 + i * 2048 + ldsbase], a_src[i] + kn);
#pragma unroll
        for (int i = 0; i < 4; i++)
            async16(&Bs[nxt * 8192 + i * 2048 + ldsbase], b_src[i] + kn);
        WAIT_VM(8);  // cur's 8 loads done; nxt's 8 still in flight
        BARRIER();
#pragma unroll
        for (int ks = 0; ks < 2; ks++) {
            bf16x8 af[4], bfr[4];
            const int cb = ks * 4 + quad;
#pragma unroll
            for (int i = 0; i < 4; i++) {
                const int r = wrow + i * 16 + l16;
                af[i] = *(const bf16x8*)(&As[cur * 8192 + (r * 8 + (cb ^ (r & 7))) * 8]);
            }
#pragma unroll
            for (int j = 0; j < 4; j++) {
                const int n = wcol + j * 16 + l16;
                bfr[j] = *(const bf16x8*)(&Bs[cur * 8192 + (n * 8 + (cb ^ (n & 7))) * 8]);
            }
#pragma unroll
            for (int i = 0; i < 4; i++)
#pragma unroll
                for (int j = 0; j < 4; j++)
                    acc[i][j] = __builtin_amdgcn_mfma_f32_16x16x32_bf16(
                        af[i], bfr[j], acc[i][j], 0, 0, 0);
        }
        BARRIER();  // protect cur before next iter overwrites it
    }

    // epilogue: C/D layout col = lane&15, row = quad*4 + reg  [m89-verified]
#pragma unroll
    for (int j = 0; j < 4; j++) {
        const int n = n0 + wcol + j * 16 + l16;
        const float bv = bias[n];
#pragma unroll
        for (int i = 0; i < 4; i++) {
            const int rbase = wrow + i * 16 + quad * 4;
#pragma unroll
            for (int r = 0; r < 4; r++) {
                const int p = m_start + rbase + r;
                if (EXPERT && p >= cnt) continue;
                float v = acc[i][j][r] + bv;
                if (GELU) v = geluf(v);
                size_t drow;
                if (EXPERT) {
                    const int pp = off + p;
                    drow = SCATTER_C ? (size_t)row_ids[pp] : (size_t)pp;
                } else {
                    drow = (size_t)p;
                }
                Cmat[drow * (size_t)N + n] = (CT)v;
            }
        }
    }
}

// ---------------------------------------------------------------------------
// Dispatch 1: prep (1024 blocks) + Ws1/Ws2 transpose (192) + bucket (1).
// Bucket is block 0 so its serial latency starts first and hides under the
// BW-bound prep/transpose blocks.
// ---------------------------------------------------------------------------
__global__ void setup_kernel(const int* __restrict__ genre,
                             const float* __restrict__ z,
                             const float* __restrict__ mu_t,
                             const float* __restrict__ sg_t,
                             bf16* __restrict__ ng,
                             const float* __restrict__ Ws1,
                             const float* __restrict__ Ws2,
                             bf16* __restrict__ WT1, bf16* __restrict__ WT2,
                             int* __restrict__ counts,
                             int* __restrict__ offsets,
                             int* __restrict__ row_ids) {
    __shared__ float T[2 * 4096];  // 32 KB; bucket aliases first 80 ints
    const int b = blockIdx.x;
    if (b == 0) {
        bucket_body(genre, counts, offsets, row_ids, (int*)T);
    } else if (b < 1025) {
        prep_body(b - 1, genre, z, mu_t, sg_t, ng);
    } else if (b < 1089) {
        transpose_body(Ws1, WT1, 512, b - 1025, T);
    } else {
        transpose_body(Ws2, WT2, 1024, b - 1089, T);
    }
}

// ---------------------------------------------------------------------------
// Dispatches 2/3: shared-MLP GEMM (256 blocks, first in grid) overlapped
// with one expert weight tensor's transpose (1280 blocks). The 60 MB of
// transpose traffic rides under the GEMM's MFMA compute.
// ---------------------------------------------------------------------------
__global__ __launch_bounds__(256, 2) void mlp_fused_kernel(
    const bf16* __restrict__ Ain, const bf16* __restrict__ WT,
    const float* __restrict__ bias, bf16* __restrict__ Sout,
    const float* __restrict__ We, bf16* __restrict__ WET, int K) {
    __shared__ bf16 smem[32768];  // 64 KB: As[2][8192] | Bs[2][8192]
    int b = blockIdx.x;
    if (b < 256) {
        gemm_body<false, false, false, true, bf16>(
            b & 7, b >> 3, 0, Ain, WT, bias, Sout, DIM, K, nullptr, nullptr,
            nullptr, smem, smem + 16384);
    } else {
        b -= 256;
        const int e = b >> 7;
        transpose_body(We + (size_t)e * DIM * DIM, WET + (size_t)e * DIM * DIM,
                       1024, b & 127, (float*)smem);
    }
}

// ---------------------------------------------------------------------------
// Dispatches 4/5: expert GEMMs. grid (8, 32, 10); blocks past the bucket
// count return immediately.
// ---------------------------------------------------------------------------
template <bool GATHER_A, bool SCATTER_C, bool GELU, typename CT>
__global__ __launch_bounds__(256, 2) void expert_gemm_kernel(
    const bf16* __restrict__ A, const bf16* __restrict__ BT,
    const float* __restrict__ bias, CT* __restrict__ Cmat,
    const int* __restrict__ row_ids, const int* __restrict__ offsets,
    const int* __restrict__ counts) {
    __shared__ bf16 smem[32768];
    gemm_body<true, GATHER_A, SCATTER_C, GELU, CT>(
        blockIdx.x, blockIdx.y, blockIdx.z, A, BT, bias, Cmat, DIM, DIM,
        row_ids, offsets, counts, smem, smem + 16384);
}

extern "C" void kernel_launch(void* const* d_in, const int* in_sizes, int n_in,
                              void* d_out, int out_size, void* d_ws,
                              size_t ws_size, hipStream_t stream) {
    const int* genre = (const int*)d_in[1];
    const float* z = (const float*)d_in[2];
    const float* mu_t = (const float*)d_in[3];
    const float* sg_t = (const float*)d_in[4];
    const float* Ws1 = (const float*)d_in[5];
    const float* bs1 = (const float*)d_in[6];
    const float* Ws2 = (const float*)d_in[7];
    const float* bs2 = (const float*)d_in[8];
    const float* We1 = (const float*)d_in[9];
    const float* be1 = (const float*)d_in[10];
    const float* We2 = (const float*)d_in[11];
    const float* be2 = (const float*)d_in[12];
    float* out = (float*)d_out;
    char* w = (char*)d_ws;

    // Workspace (~63.1 MB): ints first, weights last.
    int* counts = (int*)w;
    int* offsets = (int*)(w + 256);
    int* row_ids = (int*)(w + 1024);
    char* wb = w + (64 << 10);
    bf16* ng = (bf16*)wb;                          // [4096][512]  4 MB
    bf16* hp = (bf16*)wb;                          // [4096][1024] 8 MB (aliases ng+s1; both dead by expert1)
    bf16* s1 = (bf16*)(wb + ((size_t)4 << 20));    // 8 MB
    bf16* s2 = (bf16*)(wb + ((size_t)12 << 20));   // 8 MB
    bf16* WT1 = (bf16*)(wb + ((size_t)20 << 20));  // [1024][512]  1 MB
    bf16* WT2 = WT1 + (size_t)IN_DIM * DIM;        // [1024][1024] 2 MB
    bf16* WE1T = WT2 + (size_t)DIM * DIM;          // 10x[1024][1024] 20 MB
    bf16* WE2T = WE1T + (size_t)NG * DIM * DIM;    // 20 MB

    // D1: bucket + prep + shared-weight transposes
    setup_kernel<<<1217, 256, 0, stream>>>(genre, z, mu_t, sg_t, ng, Ws1, Ws2,
                                           WT1, WT2, counts, offsets, row_ids);
    // D2: shared MLP layer 1 (K=512)  ||  transpose We1
    mlp_fused_kernel<<<1536, 256, 0, stream>>>(ng, WT1, bs1, s1, We1, WE1T,
                                               IN_DIM);
    // D3: shared MLP layer 2 (K=1024) ||  transpose We2
    mlp_fused_kernel<<<1536, 256, 0, stream>>>(s1, WT2, bs2, s2, We2, WE2T,
                                               DIM);
    // D4: expert layer 1: gather rows by bucket, gelu, write permuted h
    expert_gemm_kernel<true, false, true, bf16>
        <<<dim3(8, 32, 10), 256, 0, stream>>>(s2, WE1T, be1, hp, row_ids,
                                              offsets, counts);
    // D5: expert layer 2: contiguous permuted h, scatter rows to fp32 out
    expert_gemm_kernel<false, true, false, float>
        <<<dim3(8, 32, 10), 256, 0, stream>>>(hp, WE2T, be2, out, row_ids,
                                              offsets, counts);
}